// Round 1
// baseline (607.443 us; speedup 1.0000x reference)
//
#include <hip/hip_runtime.h>
#include <hip/hip_bf16.h>

#define N_NODES 32768
#define N_EDGES 196608
#define N_GRAPHS 256
#define DEG 6
#define HID 128
#define RVD 16
#define EMB 112
#define VOCAB 128
#define TGT 256
#define DEPTH 5

#define LOG7 1.9459101090932196f
#define ILOG7 0.5138983423697507f

typedef __hip_bfloat16 bf16;
using frag_ab = __attribute__((ext_vector_type(8))) short;   // 8 bf16
using frag_cd = __attribute__((ext_vector_type(4))) float;   // 4 f32

static __device__ __forceinline__ float b2f(bf16 x) { return __bfloat162float(x); }
static __device__ __forceinline__ bf16  f2b(float x) { return __float2bfloat16(x); }

// ---------------- encoders ----------------
// h[v] = [sum_i atom_emb[i, af[v,i], :], rand_x[v]]  -> f32 h and bf16 hcat[:,0:128]
__global__ void encode_nodes(const int* __restrict__ af, const float* __restrict__ rx,
                             const float* __restrict__ emb, float* __restrict__ h,
                             bf16* __restrict__ hcat) {
    int v = blockIdx.x, c = threadIdx.x;
    float val;
    if (c < EMB) {
        val = 0.f;
        #pragma unroll
        for (int i = 0; i < 9; ++i) {
            int f = af[v * 9 + i];
            val += emb[(i * VOCAB + f) * EMB + c];
        }
    } else {
        val = rx[v * RVD + (c - EMB)];
    }
    h[(size_t)v * HID + c] = val;
    hcat[(size_t)v * 640 + c] = f2b(val);
}

__global__ void encode_edges(const int* __restrict__ bfeat, const float* __restrict__ re,
                             const float* __restrict__ emb, bf16* __restrict__ ef) {
    int e = blockIdx.x, c = threadIdx.x;
    float val;
    if (c < EMB) {
        val = 0.f;
        #pragma unroll
        for (int i = 0; i < 3; ++i) {
            int f = bfeat[e * 3 + i];
            val += emb[(i * VOCAB + f) * EMB + c];
        }
    } else {
        val = re[e * RVD + (c - EMB)];
    }
    ef[(size_t)e * HID + c] = f2b(val);
}

// ---------------- weight packing into MFMA B-fragment layout ----------------
// B frag elem linear index: ((ks*NT + nt)*64 + lane)*8 + j
// maps to B[k = ks*32 + (lane>>4)*8 + j][n = nt*16 + (lane&15)]

// Wb: [128,256], n<128 -> preW[k][n] (src part), n>=128 -> preW[128+k][n-128] (dst part). NT=16.
__global__ void pack_wb(const float* __restrict__ preW, bf16* __restrict__ out) {
    int idx = blockIdx.x * 256 + threadIdx.x;
    if (idx >= DEPTH * 32768) return;
    int j = idx & 7, L = (idx >> 3) & 63, nt = (idx >> 9) & 15, ks = (idx >> 13) & 3, l = idx >> 15;
    int k = ks * 32 + ((L >> 4) * 8) + j;
    int n = nt * 16 + (L & 15);
    const float* W = preW + (size_t)l * 384 * 128;
    float v = (n < 128) ? W[k * 128 + n] : W[(128 + k) * 128 + (n - 128)];
    out[idx] = f2b(v);
}

// Wp3: [128,128] = preW rows 256:384. NT=8.
__global__ void pack_wp3(const float* __restrict__ preW, bf16* __restrict__ out) {
    int idx = blockIdx.x * 256 + threadIdx.x;
    if (idx >= DEPTH * 16384) return;
    int j = idx & 7, L = (idx >> 3) & 63, nt = (idx >> 9) & 7, ks = (idx >> 12) & 3, l = idx >> 14;
    int k = ks * 32 + ((L >> 4) * 8) + j;
    int n = nt * 16 + (L & 15);
    const float* W = preW + (size_t)l * 384 * 128;
    out[idx] = f2b(W[(256 + k) * 128 + n]);
}

// Wc: [640,128]. k<128: postW[k][n]; k>=128: fold 3 scaler blocks. NT=8, ksteps=20.
__global__ void pack_wc(const float* __restrict__ postW, bf16* __restrict__ out) {
    int idx = blockIdx.x * 256 + threadIdx.x;
    if (idx >= DEPTH * 81920) return;
    int j = idx & 7, L = (idx >> 3) & 63, nt = (idx >> 9) & 7;
    int t = idx >> 12;
    int ks = t % 20, l = t / 20;
    int k = ks * 32 + ((L >> 4) * 8) + j;
    int n = nt * 16 + (L & 15);
    const float* W = postW + (size_t)l * 1664 * 128;
    float v;
    if (k < 128) {
        v = W[k * 128 + n];
    } else {
        int jj = k - 128;
        v = W[(128 + jj) * 128 + n] + LOG7 * W[(640 + jj) * 128 + n] + ILOG7 * W[(1152 + jj) * 128 + n];
    }
    out[idx] = f2b(v);
}

// ---------------- GEMM: C[M,NT*16] = A[M,K] @ Bpacked ----------------
// 4 waves/block, each wave owns RT 16-row tiles -> block covers RT*64 rows.
// EPI 0: write bf16 C (ldc). EPI 1: += bias + residual h, write f32 h and bf16 into hcat[:,0:128].
template <int NT, int RT, int EPI>
__global__ __launch_bounds__(256) void gemm_k(const bf16* __restrict__ A, int lda, int ksteps,
                                              const bf16* __restrict__ Bp,
                                              bf16* __restrict__ Cbf, int ldc,
                                              const float* __restrict__ bias,
                                              float* __restrict__ hbuf,
                                              bf16* __restrict__ hcat) {
    int lane = threadIdx.x & 63;
    int wave = threadIdx.x >> 6;
    int m = lane & 15, quad = lane >> 4;
    int row0 = blockIdx.x * (RT * 64) + wave * (RT * 16);

    frag_cd acc[RT][NT];
    #pragma unroll
    for (int rt = 0; rt < RT; ++rt)
        #pragma unroll
        for (int nt = 0; nt < NT; ++nt)
            #pragma unroll
            for (int i = 0; i < 4; ++i) acc[rt][nt][i] = 0.f;

    const frag_ab* Bf = (const frag_ab*)Bp;
    for (int ks = 0; ks < ksteps; ++ks) {
        frag_ab a[RT];
        #pragma unroll
        for (int rt = 0; rt < RT; ++rt)
            a[rt] = *(const frag_ab*)(A + (size_t)(row0 + rt * 16 + m) * lda + ks * 32 + quad * 8);
        #pragma unroll
        for (int nt = 0; nt < NT; ++nt) {
            frag_ab b = Bf[(ks * NT + nt) * 64 + lane];
            #pragma unroll
            for (int rt = 0; rt < RT; ++rt)
                acc[rt][nt] = __builtin_amdgcn_mfma_f32_16x16x32_bf16(a[rt], b, acc[rt][nt], 0, 0, 0);
        }
    }

    #pragma unroll
    for (int rt = 0; rt < RT; ++rt) {
        #pragma unroll
        for (int nt = 0; nt < NT; ++nt) {
            int col = nt * 16 + m;
            #pragma unroll
            for (int r = 0; r < 4; ++r) {
                int row = row0 + rt * 16 + quad * 4 + r;
                float v = acc[rt][nt][r];
                if (EPI == 0) {
                    Cbf[(size_t)row * ldc + col] = f2b(v);
                } else {
                    float nv = v + bias[col] + hbuf[(size_t)row * HID + col];
                    hbuf[(size_t)row * HID + col] = nv;
                    hcat[(size_t)row * 640 + col] = f2b(nv);
                }
            }
        }
    }
}

// ---------------- per-node edge aggregation ----------------
// e(v,j,c) = relu(Z1[src][c] + Z2[v][c] + Ep[e][c] + pb[c]); agg -> hcat[:,128:640]
__global__ __launch_bounds__(256) void edge_agg(const bf16* __restrict__ Z12, const bf16* __restrict__ Ep,
                                                const int* __restrict__ src, const float* __restrict__ pb,
                                                bf16* __restrict__ hcat) {
    int c = threadIdx.x & 127;
    int half = threadIdx.x >> 7;
    int v0 = blockIdx.x * 16 + half * 8;
    float bias = pb[c];
    for (int i = 0; i < 8; ++i) {
        int v = v0 + i;
        float z2 = b2f(Z12[(size_t)v * 256 + 128 + c]);
        float s = 0.f, ss = 0.f, mx = -1e30f, mn = 1e30f;
        #pragma unroll
        for (int j = 0; j < DEG; ++j) {
            int e = v * DEG + j;
            int sv = src[e];
            float val = b2f(Z12[(size_t)sv * 256 + c]) + z2 + b2f(Ep[(size_t)e * HID + c]) + bias;
            val = fmaxf(val, 0.f);
            s += val; ss += val * val; mx = fmaxf(mx, val); mn = fminf(mn, val);
        }
        float mean = s * (1.f / 6.f);
        float msq = ss * (1.f / 6.f);
        float sd = sqrtf(fmaxf(msq - mean * mean, 0.f) + 1e-5f);
        size_t base = (size_t)v * 640;
        hcat[base + 128 + c] = f2b(mean);
        hcat[base + 256 + c] = f2b(mx);
        hcat[base + 384 + c] = f2b(mn);
        hcat[base + 512 + c] = f2b(sd);
    }
}

// ---------------- readout: one block per graph ----------------
__global__ __launch_bounds__(128) void readout(const float* __restrict__ h, const float* __restrict__ W1,
                                               const float* __restrict__ b1, const float* __restrict__ W2,
                                               const float* __restrict__ b2, float* __restrict__ out) {
    __shared__ float r[384];
    __shared__ float y1[128];
    int g = blockIdx.x, c = threadIdx.x;
    float s = 0.f, mx = -1e30f;
    for (int v = 0; v < 128; ++v) {
        float hv = h[((size_t)g * 128 + v) * HID + c];
        s += hv; mx = fmaxf(mx, hv);
    }
    r[c] = s * (1.f / 128.f);
    r[128 + c] = s;
    r[256 + c] = mx;
    __syncthreads();
    float a1 = b1[c];
    for (int k = 0; k < 384; ++k) a1 += r[k] * W1[k * 128 + c];
    y1[c] = fmaxf(a1, 0.f);
    __syncthreads();
    #pragma unroll
    for (int o = 0; o < 2; ++o) {
        int t = c + o * 128;
        float a2 = b2[t];
        for (int k = 0; k < 128; ++k) a2 += y1[k] * W2[k * 256 + t];
        out[(size_t)g * 256 + t] = a2;
    }
}

// ---------------- launch ----------------
extern "C" void kernel_launch(void* const* d_in, const int* in_sizes, int n_in,
                              void* d_out, int out_size, void* d_ws, size_t ws_size,
                              hipStream_t stream) {
    const int*   atom_feats = (const int*)d_in[0];
    const int*   bond_feats = (const int*)d_in[1];
    const int*   src        = (const int*)d_in[2];
    const float* rand_x     = (const float*)d_in[6];
    const float* rand_edge  = (const float*)d_in[7];
    const float* atom_emb   = (const float*)d_in[8];
    const float* bond_emb   = (const float*)d_in[9];
    const float* pre_W      = (const float*)d_in[10];
    const float* pre_b      = (const float*)d_in[11];
    const float* post_W     = (const float*)d_in[12];
    const float* post_b     = (const float*)d_in[13];
    const float* ro_W1      = (const float*)d_in[14];
    const float* ro_b1      = (const float*)d_in[15];
    const float* ro_W2      = (const float*)d_in[16];
    const float* ro_b2      = (const float*)d_in[17];

    char* p = (char*)d_ws;
    auto alloc = [&](size_t bytes) {
        char* r = p;
        p += (bytes + 255) & ~(size_t)255;
        return r;
    };
    float* h    = (float*)alloc((size_t)N_NODES * HID * 4);      // 16 MB
    bf16*  hcat = (bf16*) alloc((size_t)N_NODES * 640 * 2);      // 40 MB  [h | mean mx mn std]
    bf16*  ef   = (bf16*) alloc((size_t)N_EDGES * HID * 2);      // 50 MB
    bf16*  z12  = (bf16*) alloc((size_t)N_NODES * 256 * 2);      // 16 MB
    bf16*  ep   = (bf16*) alloc((size_t)N_EDGES * HID * 2);      // 50 MB
    bf16*  wb   = (bf16*) alloc((size_t)DEPTH * 32768 * 2);
    bf16*  wp3  = (bf16*) alloc((size_t)DEPTH * 16384 * 2);
    bf16*  wc   = (bf16*) alloc((size_t)DEPTH * 81920 * 2);

    pack_wb <<<(DEPTH * 32768 + 255) / 256, 256, 0, stream>>>(pre_W, wb);
    pack_wp3<<<(DEPTH * 16384 + 255) / 256, 256, 0, stream>>>(pre_W, wp3);
    pack_wc <<<(DEPTH * 81920 + 255) / 256, 256, 0, stream>>>(post_W, wc);

    encode_nodes<<<N_NODES, 128, 0, stream>>>(atom_feats, rand_x, atom_emb, h, hcat);
    encode_edges<<<N_EDGES, 128, 0, stream>>>(bond_feats, rand_edge, bond_emb, ef);

    for (int l = 0; l < DEPTH; ++l) {
        // Z12[N,256] = h @ [pW_src | pW_dst]
        gemm_k<16, 1, 0><<<N_NODES / 64, 256, 0, stream>>>(
            hcat, 640, 4, wb + (size_t)l * 32768, z12, 256, nullptr, nullptr, nullptr);
        // Ep[E,128] = ef @ pW_edge
        gemm_k<8, 2, 0><<<N_EDGES / 128, 256, 0, stream>>>(
            ef, 128, 4, wp3 + (size_t)l * 16384, ep, 128, nullptr, nullptr, nullptr);
        // aggregation -> hcat[:,128:640]
        edge_agg<<<N_NODES / 16, 256, 0, stream>>>(z12, ep, src, pre_b + l * HID, hcat);
        // h = hcat[:,0:640] @ Wc + qb + h ; hcat[:,0:128] = bf16(h)
        gemm_k<8, 2, 1><<<N_NODES / 128, 256, 0, stream>>>(
            hcat, 640, 20, wc + (size_t)l * 81920, nullptr, 0, post_b + l * HID, h, hcat);
    }

    readout<<<N_GRAPHS, 128, 0, stream>>>(h, ro_W1, ro_b1, ro_W2, ro_b2, (float*)d_out);
}